// Round 1
// baseline (259.312 us; speedup 1.0000x reference)
//
#include <hip/hip_runtime.h>

#define NUM_BINS 15
#define NB 4096            // blocks; each owns a contiguous 2048-float4 chunk (32 KB/array)
#define NT 256
#define NCOMP 45           // ws rows: cnt[15] | acc[15] | conf[15]
#define INV15 0.066666667f

// native clang vector types — required by __builtin_nontemporal_load
typedef float vfloat4 __attribute__((ext_vector_type(4)));
typedef int   vint4   __attribute__((ext_vector_type(4)));

// One uint32 per element: [31:24] label, [23:16] 1, [15:0] round((p-bin/15)*4096).
// Per-thread totals (32 elem): cnt<=32, acc<=32, res<=32*274=8768 -> no field overflow.
__device__ __forceinline__ unsigned pack_elem(float pv, int lv, int* bin_out) {
    int bin = (int)ceilf(pv * 15.0f) - 1;      // matches jnp ceil(p*15)-1 in fp32
    bin = (min(max(bin, -1), 15)) & 15;        // invalid (p<=0 | p>1) -> 15 (dump row)
    *bin_out = bin;
    float x = fmaf(pv, 4096.0f, fmaf((float)bin, -4096.0f * INV15, 0.5f));
    unsigned rq = (unsigned)x;                 // v_cvt_u32_f32 saturates negatives to 0
    return ((unsigned)lv << 24) + 0x10000u + rq;
}

struct Batch { vfloat4 p0, p1; vint4 l0, l1; };

__device__ __forceinline__ void load_batch(Batch& b, const vfloat4* __restrict__ p4,
                                           const vint4* __restrict__ l4, int j, int t) {
    const int o = (j << 9) + t;
    b.p0 = __builtin_nontemporal_load(&p4[o]);
    b.p1 = __builtin_nontemporal_load(&p4[o + 256]);
    b.l0 = __builtin_nontemporal_load(&l4[o]);
    b.l1 = __builtin_nontemporal_load(&l4[o + 256]);
}

// Fire-and-forget LDS atomics (ds_add_u32, no return): no ds_read, no lgkmcnt
// dependency chain, no duplicate-bin merge logic. Same-address adds from one
// lane's 4 elements are serialized by the LDS atomic unit for free.
// Bank = t%32 is distinct per lane within each 32-lane half -> conflict-free.
__device__ __forceinline__ void scatter4(unsigned* histT, vfloat4 p, vint4 l) {
    int b0, b1, b2, b3;
    unsigned k0 = pack_elem(p.x, l.x, &b0);
    unsigned k1 = pack_elem(p.y, l.y, &b1);
    unsigned k2 = pack_elem(p.z, l.z, &b2);
    unsigned k3 = pack_elem(p.w, l.w, &b3);
    atomicAdd(&histT[b0 << 8], k0);
    atomicAdd(&histT[b1 << 8], k1);
    atomicAdd(&histT[b2 << 8], k2);
    atomicAdd(&histT[b3 << 8], k3);
}

__device__ __forceinline__ void consume(const Batch& b, unsigned* histT) {
    scatter4(histT, b.p0, b.l0);
    scatter4(histT, b.p1, b.l1);
}

__global__ __launch_bounds__(NT, 6) void ece_partial(
    const float* __restrict__ probs, const int* __restrict__ labels,
    float* __restrict__ ws, int n4)
{
    __shared__ unsigned hist[16 * NT];   // 16 KB: cell[bin][t], bank = t%32, conflict-free
    const int t = threadIdx.x;

    uint4* h4 = (uint4*)hist;
#pragma unroll
    for (int i = 0; i < 4; ++i) h4[i * NT + t] = uint4{0u, 0u, 0u, 0u};
    __syncthreads();

    const int base = blockIdx.x * 2048;          // float4 units
    const vfloat4* __restrict__ p4 = (const vfloat4*)probs + base;
    const vint4*   __restrict__ l4 = (const vint4*)labels + base;
    unsigned* histT = hist + t;

    if (base + 2048 <= n4) {
        // double-buffered pipeline: batch j+1's 4 loads are in flight while batch j
        // is consumed; sched_barrier(0) pins the issue order.
        Batch A, B;
        load_batch(A, p4, l4, 0, t);
        load_batch(B, p4, l4, 1, t);
        __builtin_amdgcn_sched_barrier(0);
        consume(A, histT);
        load_batch(A, p4, l4, 2, t);
        __builtin_amdgcn_sched_barrier(0);
        consume(B, histT);
        load_batch(B, p4, l4, 3, t);
        __builtin_amdgcn_sched_barrier(0);
        consume(A, histT);
        consume(B, histT);
    } else {
        // guarded tail path (unused at N=2^25; kept for generality)
        for (int j = 0; j < 8; ++j) {
            const int idx = (j << 8) + t;
            if (base + idx < n4) {
                vfloat4 p = p4[idx];
                vint4   l = l4[idx];
                scatter4(histT, p, l);
            }
        }
    }
    __syncthreads();

    // cross-thread reduce: row r = t>>4 (0..15), strip s = t&15 (16 cells each)
    const int r = t >> 4, s = t & 15;
    float csum = 0.f, asum = 0.f, rsum = 0.f;
#pragma unroll
    for (int k = 0; k < 16; ++k) {
        unsigned v = hist[(r << 8) + (s << 4) + k];
        asum += (float)(v >> 24);
        csum += (float)((v >> 16) & 0xFFu);
        rsum += (float)(v & 0xFFFFu);
    }
#pragma unroll
    for (int o = 8; o; o >>= 1) {    // 16-lane strips are wave-aligned
        csum += __shfl_down(csum, o);
        asum += __shfl_down(asum, o);
        rsum += __shfl_down(rsum, o);
    }
    if (s == 0 && r < NUM_BINS) {
        float conf = fmaf(csum, (float)r * INV15, rsum * 2.44140625e-4f);
        ws[r * NB + blockIdx.x]                  = csum;
        ws[(NUM_BINS + r) * NB + blockIdx.x]     = asum;
        ws[(2 * NUM_BINS + r) * NB + blockIdx.x] = conf;
    }
}

// Final: 16 waves reduce the [45][NB] partials (720 KB) and emit scalar ECE.
__global__ __launch_bounds__(1024) void ece_final(
    const float* __restrict__ ws, float* __restrict__ out, float n)
{
    __shared__ float sums[NCOMP];
    const int wave = threadIdx.x >> 6;
    const int lane = threadIdx.x & 63;

    for (int c = wave; c < NCOMP; c += 16) {
        const float4* row4 = (const float4*)(ws + c * NB);
        float s = 0.f;
#pragma unroll
        for (int k = 0; k < NB / 256; ++k) {
            float4 v = row4[lane + (k << 6)];
            s += (v.x + v.y) + (v.z + v.w);
        }
#pragma unroll
        for (int o = 32; o; o >>= 1) s += __shfl_down(s, o);
        if (lane == 0) sums[c] = s;
    }
    __syncthreads();

    if (threadIdx.x == 0) {
        float ece = 0.f;
#pragma unroll
        for (int b = 0; b < NUM_BINS; ++b) {
            float cnt = sums[b];
            float acc = sums[NUM_BINS + b];
            float cf  = sums[2 * NUM_BINS + b];
            float denom = fmaxf(cnt, 1.f);
            ece += (cnt / n) * fabsf(acc / denom - cf / denom);
        }
        out[0] = ece;
    }
}

extern "C" void kernel_launch(void* const* d_in, const int* in_sizes, int n_in,
                              void* d_out, int out_size, void* d_ws, size_t ws_size,
                              hipStream_t stream)
{
    const float* probs  = (const float*)d_in[0];
    const int*   labels = (const int*)d_in[1];
    const int n = in_sizes[0];   // 33,554,432

    ece_partial<<<NB, NT, 0, stream>>>(probs, labels, (float*)d_ws, n / 4);
    ece_final<<<1, 1024, 0, stream>>>((const float*)d_ws, (float*)d_out, (float)n);
}